// Round 12
// baseline (251.148 us; speedup 1.0000x reference)
//
#include <hip/hip_runtime.h>
#include <cstdint>
#include <cmath>

#define Bn 4096
#define Dn 256
#define On 256

typedef __bf16 v8bf __attribute__((ext_vector_type(8)));
typedef float  v16f __attribute__((ext_vector_type(16)));
typedef unsigned short us8 __attribute__((ext_vector_type(8)));

__device__ __forceinline__ unsigned short f2bf(float f) {
    // round-to-nearest-even fp32 -> bf16 (inputs are finite normals)
    unsigned int u = __builtin_bit_cast(unsigned int, f);
    unsigned int r = (u + 0x7fffu + ((u >> 16) & 1u)) >> 16;
    return (unsigned short)r;
}

__device__ __forceinline__ void gl_lds16(const void* g, void* l) {
    __builtin_amdgcn_global_load_lds(
        (const __attribute__((address_space(1))) void*)(uintptr_t)g,
        (__attribute__((address_space(3))) void*)(uintptr_t)l, 16, 0, 0);
}

// ---------------------------------------------------------------------------
// Kernel 1: FUSED prep — round-7 version (validated passing, absmax 2.44e-4).
// Blocks [0,2560): build A' = 32x32x16 MFMA A-operand order of
// (triu(rots,1)+triu^T+diag(scales)), bf16:
//   A'[(o*8+s)*16+t][lane][j] = A[o][i=s*32+(lane&31)][k=t*16+(lane>>5)*8+j]
// 1KB per (o, 32-i-strip s, 16-k-step t). Blocks [2560,2816): x -> bf16.
// ---------------------------------------------------------------------------
__global__ __launch_bounds__(256) void prep(
    const float* __restrict__ scales, const float* __restrict__ rots,
    const float* __restrict__ x, unsigned short* __restrict__ Ap,
    unsigned short* __restrict__ xb) {
    const int bid = blockIdx.x;
    const int tid = threadIdx.x;

    if (bid >= 2560) {                   // ---- cvt_x part: 256 blocks ----
        const int cb = bid - 2560;
#pragma unroll
        for (int s = 0; s < 4; ++s) {
            const int i = cb * 4096 + s * 1024 + tid * 4;
            const float4 v = *(const float4*)(x + i);
            ushort4 u;
            u.x = f2bf(v.x); u.y = f2bf(v.y); u.z = f2bf(v.z); u.w = f2bf(v.w);
            *(ushort4*)(xb + i) = u;
        }
        return;
    }

    // ---- build_A' part: 2560 blocks, one per unordered 64x64 tile pair ----
    static const int TI[10] = {0, 0, 0, 0, 1, 1, 1, 2, 2, 3};
    static const int TJ[10] = {0, 1, 2, 3, 1, 2, 3, 2, 3, 3};
    const int o  = bid / 10;
    const int p  = bid - o * 10;
    const int ti = TI[p], tj = TJ[p];

    __shared__ float t[64][68];          // 16B-aligned rows, padded banks
    const float* src = rots + (size_t)o * Dn * Dn + (size_t)(ti * 64) * Dn + tj * 64;
#pragma unroll
    for (int s = 0; s < 4; ++s) {
        const int idx = s * 256 + tid;
        const int r = idx >> 4, c = (idx & 15) * 4;
        const float4 v = *(const float4*)(src + r * Dn + c);
        *(float4*)&t[r][c] = v;
    }
    __syncthreads();

    const int L   = tid & 63;
    const int kl  = (tid >> 6) & 3;      // local 16-k-step, 0..3
    const int i32 = L & 31;
    const int kb  = kl * 16 + (L >> 5) * 8;   // local k base, 0..56

    // phase U: output strips of row-tile ti, ksteps of col-tile tj
#pragma unroll
    for (int it = 0; it < 2; ++it) {
        const int r = it * 32 + i32;     // local row (= i within tile)
        float v[8];
        if (ti == tj) {
#pragma unroll
            for (int q = 0; q < 8; ++q) {
                const int cc = kb + q;
                v[q] = (r < cc) ? t[r][cc]
                     : ((r > cc) ? t[cc][r] : scales[o * Dn + ti * 64 + r]);
            }
        } else {
            const float4 a = *(const float4*)&t[r][kb];
            const float4 b = *(const float4*)&t[r][kb + 4];
            v[0] = a.x; v[1] = a.y; v[2] = a.z; v[3] = a.w;
            v[4] = b.x; v[5] = b.y; v[6] = b.z; v[7] = b.w;
        }
        us8 u;
#pragma unroll
        for (int q = 0; q < 8; ++q) u[q] = f2bf(v[q]);
        const size_t off = ((size_t)((o * 8 + ti * 2 + it) * 16 + tj * 4 + kl)) * 512 + L * 8;
        *(us8*)(Ap + off) = u;           // 64 consecutive L -> 1KB coalesced
    }

    if (ti != tj) {                      // phase L: mirror tile (tj,ti), transposed
#pragma unroll
        for (int it = 0; it < 2; ++it) {
            const int r = it * 32 + i32; // local row of the OUTPUT (mirror) tile
            us8 u;
#pragma unroll
            for (int q = 0; q < 8; ++q) u[q] = f2bf(t[kb + q][r]);
            const size_t off = ((size_t)((o * 8 + tj * 2 + it) * 16 + ti * 4 + kl)) * 512 + L * 8;
            *(us8*)(Ap + off) = u;
        }
    }
}

// ---------------------------------------------------------------------------
// Kernel 2: fused GEMM + norm + bell — A-RESIDENT (r11-proven structure) on
// 32x32x16 MFMA (r7-validated maps; 2382 vs 2075 TF ceiling, HALF the MFMA
// instruction count: 64/iter vs 128). One block = one o x half the batch;
// each wave holds its 64-i A'-strip in regs (af[2][16] = 128 VGPR, A read
// once from HBM). Per btile iter: prefetch next Xs into the other LDS buffer
// in B-FRAGMENT IDENTITY ORDER (lane-linear ds_read_b128 -> 0 conflicts by
// construction, r7-proven), 16 ksteps x 4 MFMA (~2160-cyc burst covers
// staging), epilogue = pure fma(y,y,v) since acc is INITIALIZED from the
// centroids (saves 64 VALU adds/iter). ssbuf parity-double-buffered.
// Budget: af 128 + acc 64(AGPR) + cv 32 + xf 8 + addr ~16 ~= 248 <= 256.
// Grid 512 = 8 XCD x 32 o x 2 bhalf (o pinned to XCD, r11-proven residency).
// ---------------------------------------------------------------------------
__global__ __launch_bounds__(256, 2) void fuzzy_main(
    const unsigned short* __restrict__ Ap, const unsigned short* __restrict__ xb,
    const float* __restrict__ cent, const float* __restrict__ bvals,
    float* __restrict__ out) {
    __shared__ __align__(16) unsigned short Xs[2][32 * 512];  // 2 x 32 KB dbuf
    __shared__ float ssbuf[2][4][64];                         // parity dbuf

    const int tid  = threadIdx.x;
    const int lane = tid & 63;
    const int wv   = tid >> 6;
    // grid 512 = 8 xcd x 32 olow x 2 bhalf
    const int Lb = blockIdx.x;
    const int o     = (Lb & 7) * 32 + ((Lb >> 3) & 31);
    const int bhalf = Lb >> 8;

    const int c32  = lane & 31;          // b-col within 32-strip / i within strip
    const int half = lane >> 5;

    // centroid regs for this wave's 64 i-rows, in C/D layout order:
    // row i = wv*64 + mi*32 + (rg&3) + 8*(rg>>2) + 4*half
    float cv[2][16];
#pragma unroll
    for (int mi = 0; mi < 2; ++mi)
#pragma unroll
        for (int rg = 0; rg < 16; ++rg)
            cv[mi][rg] = cent[o * Dn + wv * 64 + mi * 32 +
                              (rg & 3) + 8 * (rg >> 2) + 4 * half];

    // ---- load this wave's ENTIRE A'-strip into registers (once) ----
    // af[mi][t] = A-frag for i-strip (wv*2+mi), kstep t (r7 layout)
    const unsigned short* Aw = Ap + (size_t)((o * 8 + wv * 2) * 16) * 512;
    v8bf af[2][16];                      // 128 VGPRs
#pragma unroll
    for (int mi = 0; mi < 2; ++mi)
#pragma unroll
        for (int t = 0; t < 16; ++t)
            af[mi][t] = *(const v8bf*)(Aw + (size_t)(mi * 16 + t) * 512 + lane * 8);

    // staging helper offsets (B-frag identity order): chunk R = t*2 + nb holds
    // B[k = t*16 + half*8 + j][col = nb*32 + c32] at lane*16
    const int srow = (lane & 31);        // source b-row within 32-strip
    const int skof = half * 8;           // source k sub-offset

    // ---- stage btile 0 into buffer 0 (8 chunks per wave) ----
    {
        const int b0 = bhalf * 2048;
#pragma unroll
        for (int q = 0; q < 8; ++q) {
            const int R  = wv * 8 + q;
            const int tt = R >> 1, nb = R & 1;
            gl_lds16(xb + (size_t)(b0 + nb * 32 + srow) * Dn + tt * 16 + skof,
                     &Xs[0][R * 512 + lane * 8]);
        }
    }
    __syncthreads();

    for (int it = 0; it < 32; ++it) {
        const int buf = it & 1;
        const int b0  = bhalf * 2048 + it * 64;
        if (it < 31) {                   // prefetch next btile into other buffer
            const int nb0 = b0 + 64;
#pragma unroll
            for (int q = 0; q < 8; ++q) {
                const int R  = wv * 8 + q;
                const int tt = R >> 1, nb = R & 1;
                gl_lds16(xb + (size_t)(nb0 + nb * 32 + srow) * Dn + tt * 16 + skof,
                         &Xs[buf ^ 1][R * 512 + lane * 8]);
            }
        }

        // acc INIT = centroid (each (row,col) cell gets +c[row] once)
        v16f acc[2][2];
#pragma unroll
        for (int mi = 0; mi < 2; ++mi)
#pragma unroll
            for (int nb = 0; nb < 2; ++nb)
#pragma unroll
                for (int rg = 0; rg < 16; ++rg)
                    acc[mi][nb][rg] = cv[mi][rg];

#pragma unroll
        for (int t = 0; t < 16; ++t) {
            v8bf xf[2];
#pragma unroll
            for (int nb = 0; nb < 2; ++nb)   // lane-linear: 0 conflicts
                xf[nb] = *(const v8bf*)&Xs[buf][(t * 2 + nb) * 512 + lane * 8];
#pragma unroll
            for (int mi = 0; mi < 2; ++mi)
#pragma unroll
                for (int nb = 0; nb < 2; ++nb)
                    acc[mi][nb] = __builtin_amdgcn_mfma_f32_32x32x16_bf16(
                        af[mi][t], xf[nb], acc[mi][nb], 0, 0, 0);
        }

        // epilogue: v = sum over this wave's 64 i of y^2 (y = acc already
        // centroid-shifted). C/D map (r7-validated): col = c32 (b), rows as cv.
#pragma unroll
        for (int nb = 0; nb < 2; ++nb) {
            float v = 0.f;
#pragma unroll
            for (int mi = 0; mi < 2; ++mi)
#pragma unroll
                for (int rg = 0; rg < 16; ++rg)
                    v = fmaf(acc[mi][nb][rg], acc[mi][nb][rg], v);
            v += __shfl_xor(v, 32);      // merge the two lane-halves (same col)
            if (lane < 32) ssbuf[buf][wv][nb * 32 + lane] = v;
        }
        __syncthreads();   // staging of buf^1 complete (covered by MFMA burst);
                           // ssbuf[buf] visible; next iter uses buf^1 only
        if (tid < 64) {
            const float ssq = ssbuf[buf][0][tid] + ssbuf[buf][1][tid] +
                              ssbuf[buf][2][tid] + ssbuf[buf][3][tid];
            out[(size_t)(b0 + tid) * On + o] = 1.0f / (1.0f + powf(ssq, bvals[o]));
        }
    }
}

// ---------------------------------------------------------------------------
// Fallback (only if d_ws is too small): exact fp32, slow but correct.
// ---------------------------------------------------------------------------
__global__ void fallback_kernel(const float* __restrict__ x, const float* __restrict__ scales,
                                const float* __restrict__ rots, const float* __restrict__ cent,
                                const float* __restrict__ bvals, float* __restrict__ out) {
    const int b = blockIdx.x * blockDim.x + threadIdx.x;
    const int o = blockIdx.y;
    if (b >= Bn) return;
    const float* R  = rots + (size_t)o * Dn * Dn;
    const float* xv = x + (size_t)b * Dn;
    float ss = 0.f;
    for (int i = 0; i < Dn; ++i) {
        float a = cent[o * Dn + i];
        for (int j = 0; j < Dn; ++j) {
            const float w = (j > i) ? R[i * Dn + j]
                          : ((j < i) ? R[j * Dn + i] : scales[o * Dn + i]);
            a += w * xv[j];
        }
        ss += a * a;
    }
    out[(size_t)b * On + o] = 1.f / (1.f + powf(ss, bvals[o]));
}

extern "C" void kernel_launch(void* const* d_in, const int* in_sizes, int n_in,
                              void* d_out, int out_size, void* d_ws, size_t ws_size,
                              hipStream_t stream) {
    const float* x         = (const float*)d_in[0];
    const float* scales    = (const float*)d_in[1];
    const float* rots      = (const float*)d_in[2];
    const float* centroids = (const float*)d_in[3];
    const float* bvals     = (const float*)d_in[4];
    float* out = (float*)d_out;

    const size_t needA = (size_t)On * Dn * Dn * sizeof(unsigned short); // 33.5 MB
    const size_t needX = (size_t)Bn * Dn * sizeof(unsigned short);      //  2.1 MB

    if (ws_size >= needA + needX) {
        unsigned short* Ap = (unsigned short*)d_ws;
        unsigned short* xb = (unsigned short*)((char*)d_ws + needA);
        prep<<<dim3(2816), 256, 0, stream>>>(scales, rots, x, Ap, xb);
        fuzzy_main<<<dim3(512), 256, 0, stream>>>(Ap, xb, centroids, bvals, out);
    } else {
        fallback_kernel<<<dim3(Bn / 256, On), 256, 0, stream>>>(x, scales, rots, centroids,
                                                                bvals, out);
    }
}